// Round 1
// baseline (369.126 us; speedup 1.0000x reference)
//
#include <hip/hip_runtime.h>

typedef unsigned short u16;
typedef __attribute__((ext_vector_type(8))) short bf16x8;
typedef __attribute__((ext_vector_type(4))) float f32x4;
typedef __attribute__((ext_vector_type(4))) unsigned short u16x4;

#define DIM 1024
#define NH 16
#define HD 64
#define BATCH 4
#define SEQ 2048
#define MROWS (BATCH * SEQ)  // 8192

__device__ __forceinline__ u16 f2bf(float f) {
  unsigned u = __builtin_bit_cast(unsigned, f);
  return (u16)((u + 0x7fffu + ((u >> 16) & 1u)) >> 16);  // RNE
}

__device__ __forceinline__ void gload16(const u16* g, u16* l) {
  __builtin_amdgcn_global_load_lds(
      (const __attribute__((address_space(1))) void*)g,
      (__attribute__((address_space(3))) void*)l, 16, 0, 0);
}

// ---------------- fp32 -> bf16 conversion (optionally scaled) ----------------
__global__ __launch_bounds__(256) void cvt_kernel(const float* __restrict__ in,
                                                  u16* __restrict__ out,
                                                  int n4, float mul) {
  int i = blockIdx.x * blockDim.x + threadIdx.x;
  int stride = gridDim.x * blockDim.x;
  for (; i < n4; i += stride) {
    f32x4 v = ((const f32x4*)in)[i];
    u16x4 o;
    o[0] = f2bf(v[0] * mul);
    o[1] = f2bf(v[1] * mul);
    o[2] = f2bf(v[2] * mul);
    o[3] = f2bf(v[3] * mul);
    ((u16x4*)out)[i] = o;
  }
}

// ---------------- GEMM: C = A * B^T + bias, A[M][K], B[N][K] bf16 ----------------
// 128x128 tile, BK=64, 4 waves (2x2), 16x16x32 bf16 MFMA.
// LDS staged via global_load_lds(16B) with XOR slot swizzle (slot ^= row&7) applied
// to the GLOBAL source address; ds_read applies the same swizzle.
enum { EPI_QK = 0, EPI_VT = 1, EPI_F32 = 2 };

#define BM 128
#define BN 128
#define BK 64

template <int EPI>
__global__ __launch_bounds__(256) void gemm_nt(const u16* __restrict__ A,
                                               const u16* __restrict__ Bm,
                                               void* __restrict__ C,
                                               const float* __restrict__ bias,
                                               float bscale, int Kdim) {
  __shared__ __attribute__((aligned(16))) u16 Alds[BM * BK];
  __shared__ __attribute__((aligned(16))) u16 Blds[BN * BK];

  const int tid = threadIdx.x;
  const int w = tid >> 6, l = tid & 63;
  const int wr = w >> 1, wc = w & 1;
  const int row0 = blockIdx.y * BM;
  const int col0 = blockIdx.x * BN;
  const int lr = l >> 3;  // row within 8-row chunk
  const int sp = l & 7;   // physical 16B slot

  f32x4 acc[4][4];
#pragma unroll
  for (int i = 0; i < 4; i++)
#pragma unroll
    for (int j = 0; j < 4; j++) {
      f32x4 z = {0.f, 0.f, 0.f, 0.f};
      acc[i][j] = z;
    }

  for (int k0 = 0; k0 < Kdim; k0 += BK) {
    __syncthreads();  // previous-iter LDS reads done
#pragma unroll
    for (int q = 0; q < 4; q++) {
      int chunk = w * 4 + q;       // 0..15
      int r = chunk * 8 + lr;      // 0..127
      int sl = sp ^ (r & 7);       // logical slot this lane fetches
      gload16(A + (size_t)(row0 + r) * Kdim + k0 + sl * 8, &Alds[chunk * 512]);
      gload16(Bm + (size_t)(col0 + r) * Kdim + k0 + sl * 8, &Blds[chunk * 512]);
    }
    __syncthreads();  // vmcnt(0) drained before barrier

#pragma unroll
    for (int t = 0; t < 2; t++) {
      int slot = (t * 4 + (l >> 4)) ^ (l & 7);
      bf16x8 af[4], bf[4];
#pragma unroll
      for (int i = 0; i < 4; i++) {
        int arow = wr * 64 + i * 16 + (l & 15);
        af[i] = *(const bf16x8*)&Alds[arow * 64 + slot * 8];
        int brow = wc * 64 + i * 16 + (l & 15);
        bf[i] = *(const bf16x8*)&Blds[brow * 64 + slot * 8];
      }
#pragma unroll
      for (int i = 0; i < 4; i++)
#pragma unroll
        for (int j = 0; j < 4; j++)
          acc[i][j] = __builtin_amdgcn_mfma_f32_16x16x32_bf16(af[i], bf[j],
                                                              acc[i][j], 0, 0, 0);
    }
  }

// epilogue: C/D layout col = lane&15, row = (lane>>4)*4 + reg
#pragma unroll
  for (int i = 0; i < 4; i++) {
#pragma unroll
    for (int j = 0; j < 4; j++) {
#pragma unroll
      for (int q = 0; q < 4; q++) {
        int m = row0 + wr * 64 + i * 16 + (l >> 4) * 4 + q;
        int n = col0 + wc * 64 + j * 16 + (l & 15);
        float v = acc[i][j][q];
        if (EPI == EPI_QK) {
          // scatter to [B, H, S, HD] bf16, bias over n (scaled)
          v += bias[n] * bscale;
          int b_ = m >> 11, s_ = m & (SEQ - 1), h_ = n >> 6, hd_ = n & 63;
          ((u16*)C)[(((size_t)(b_ * NH + h_) * SEQ + s_) << 6) + hd_] = f2bf(v);
        } else if (EPI == EPI_VT) {
          // C'[i][j] = V[token j][chan i]; scatter to [B, H, HD, S] bf16, bias over m
          v += bias[m];
          int b_ = n >> 11, s_ = n & (SEQ - 1);
          ((u16*)C)[((size_t)(b_ * NH + (m >> 6)) * HD + (m & 63)) * SEQ + s_] =
              f2bf(v);
        } else {
          // plain fp32 [M][N]
          v += bias[n];
          ((float*)C)[(size_t)m * DIM + n] = v;
        }
      }
    }
  }
}

// ---------------- flash attention ----------------
// grid (SEQ/64, BATCH*NH), 256 threads. Wave w owns 16 Q rows. KV tile = 64.
// Qh [B,H,S,HD], Kh [B,H,S,HD], Vt [B,H,HD,S] (pre-transposed), AO [B,S,DIM] bf16.
__global__ __launch_bounds__(256) void attn_kernel(const u16* __restrict__ Qh,
                                                   const u16* __restrict__ Kh,
                                                   const u16* __restrict__ Vt,
                                                   u16* __restrict__ AO) {
  __shared__ __attribute__((aligned(16))) u16 Klds[64 * 64];
  __shared__ __attribute__((aligned(16))) u16 Vlds[64 * 64];
  __shared__ __attribute__((aligned(16))) u16 Plds[4][16 * 72];  // pad 72 -> 2-way

  const int tid = threadIdx.x;
  const int w = tid >> 6, l = tid & 63;
  const int bh = blockIdx.y;  // b*NH + h
  const int qt = blockIdx.x;
  const int b_ = bh >> 4, h_ = bh & 15;
  const int lr = l >> 3, sp = l & 7;

  // Q fragments in registers (A-operand: row = lane&15, k = (lane>>4)*8 + j)
  const int qrow = qt * 64 + w * 16 + (l & 15);
  const u16* qp = Qh + ((size_t)bh * SEQ + qrow) * HD + (l >> 4) * 8;
  bf16x8 qf[2];
  qf[0] = *(const bf16x8*)qp;
  qf[1] = *(const bf16x8*)(qp + 32);

  f32x4 oacc[4];
#pragma unroll
  for (int dj = 0; dj < 4; dj++) {
    f32x4 z = {0.f, 0.f, 0.f, 0.f};
    oacc[dj] = z;
  }
  float mrun[4], lrun[4];
#pragma unroll
  for (int q = 0; q < 4; q++) {
    mrun[q] = -1e30f;
    lrun[q] = 0.f;
  }

  for (int kt = 0; kt < SEQ / 64; kt++) {
    __syncthreads();
#pragma unroll
    for (int q2 = 0; q2 < 2; q2++) {
      int chunk = w * 2 + q2;  // 0..7
      int r = chunk * 8 + lr;  // 0..63
      int sl = sp ^ (r & 7);
      gload16(Kh + ((size_t)bh * SEQ + kt * 64 + r) * HD + sl * 8,
              &Klds[chunk * 512]);
      gload16(Vt + ((size_t)bh * HD + r) * SEQ + kt * 64 + sl * 8,
              &Vlds[chunk * 512]);
    }
    __syncthreads();

    // S = Q K^T  (scale pre-folded into Wq)
    f32x4 sacc[4];
#pragma unroll
    for (int nj = 0; nj < 4; nj++) {
      f32x4 z = {0.f, 0.f, 0.f, 0.f};
      sacc[nj] = z;
    }
#pragma unroll
    for (int t = 0; t < 2; t++) {
      int slot = (t * 4 + (l >> 4)) ^ (l & 7);
#pragma unroll
      for (int nj = 0; nj < 4; nj++) {
        int krow = nj * 16 + (l & 15);
        bf16x8 kf = *(const bf16x8*)&Klds[krow * 64 + slot * 8];
        sacc[nj] =
            __builtin_amdgcn_mfma_f32_16x16x32_bf16(qf[t], kf, sacc[nj], 0, 0, 0);
      }
    }

    // online softmax: row r=(l>>4)*4+q lives in 16 lanes of group (l>>4)
    float fac[4], psum[4], mnew[4];
#pragma unroll
    for (int q = 0; q < 4; q++) {
      float pm = fmaxf(fmaxf(sacc[0][q], sacc[1][q]),
                       fmaxf(sacc[2][q], sacc[3][q]));
#pragma unroll
      for (int mm = 1; mm <= 8; mm <<= 1) pm = fmaxf(pm, __shfl_xor(pm, mm));
      mnew[q] = fmaxf(mrun[q], pm);
      fac[q] = __expf(mrun[q] - mnew[q]);
      psum[q] = 0.f;
    }
#pragma unroll
    for (int nj = 0; nj < 4; nj++) {
#pragma unroll
      for (int q = 0; q < 4; q++) {
        float p = __expf(sacc[nj][q] - mnew[q]);
        psum[q] += p;
        Plds[w][((l >> 4) * 4 + q) * 72 + nj * 16 + (l & 15)] = f2bf(p);
      }
    }
#pragma unroll
    for (int q = 0; q < 4; q++) {
#pragma unroll
      for (int mm = 1; mm <= 8; mm <<= 1) psum[q] += __shfl_xor(psum[q], mm);
      lrun[q] = lrun[q] * fac[q] + psum[q];
      mrun[q] = mnew[q];
    }
#pragma unroll
    for (int dj = 0; dj < 4; dj++) {
      f32x4 o = oacc[dj];
#pragma unroll
      for (int q = 0; q < 4; q++) o[q] *= fac[q];
      oacc[dj] = o;
    }

    // O += P V   (P from per-wave LDS, V from transposed tile)
#pragma unroll
    for (int t = 0; t < 2; t++) {
      bf16x8 pf =
          *(const bf16x8*)&Plds[w][(l & 15) * 72 + t * 32 + (l >> 4) * 8];
      int slot = (t * 4 + (l >> 4)) ^ (l & 7);
#pragma unroll
      for (int dj = 0; dj < 4; dj++) {
        int vrow = dj * 16 + (l & 15);
        bf16x8 vf = *(const bf16x8*)&Vlds[vrow * 64 + slot * 8];
        oacc[dj] =
            __builtin_amdgcn_mfma_f32_16x16x32_bf16(pf, vf, oacc[dj], 0, 0, 0);
      }
    }
  }

  // normalize + store AO [B,S,DIM]
#pragma unroll
  for (int dj = 0; dj < 4; dj++) {
#pragma unroll
    for (int q = 0; q < 4; q++) {
      int srow = qt * 64 + w * 16 + (l >> 4) * 4 + q;
      float v = oacc[dj][q] / lrun[q];
      AO[((size_t)b_ * SEQ + srow) * DIM + h_ * HD + dj * 16 + (l & 15)] = f2bf(v);
    }
  }
}

// ---------------- LayerNorm (in-place capable) ----------------
__global__ __launch_bounds__(256) void ln_kernel(const float* __restrict__ X,
                                                 const float* __restrict__ gamma,
                                                 const float* __restrict__ beta,
                                                 float* __restrict__ out) {
  __shared__ float red[8];
  const int row = blockIdx.x;
  const int tid = threadIdx.x;
  const float* xr = X + (size_t)row * DIM;
  f32x4 v = ((const f32x4*)xr)[tid];
  float s = v[0] + v[1] + v[2] + v[3];
  float ss = v[0] * v[0] + v[1] * v[1] + v[2] * v[2] + v[3] * v[3];
#pragma unroll
  for (int mm = 1; mm <= 32; mm <<= 1) {
    s += __shfl_xor(s, mm);
    ss += __shfl_xor(ss, mm);
  }
  const int w = tid >> 6, l = tid & 63;
  if (l == 0) {
    red[w * 2] = s;
    red[w * 2 + 1] = ss;
  }
  __syncthreads();
  s = red[0] + red[2] + red[4] + red[6];
  ss = red[1] + red[3] + red[5] + red[7];
  float mu = s * (1.f / DIM);
  float var = ss * (1.f / DIM) - mu * mu;
  float rstd = rsqrtf(var + 1e-5f);
  f32x4 g = ((const f32x4*)gamma)[tid];
  f32x4 bt = ((const f32x4*)beta)[tid];
  f32x4 o;
#pragma unroll
  for (int j = 0; j < 4; j++) o[j] = (v[j] - mu) * rstd * g[j] + bt[j];
  ((f32x4*)(out + (size_t)row * DIM))[tid] = o;
}

// ---------------- launch ----------------
extern "C" void kernel_launch(void* const* d_in, const int* in_sizes, int n_in,
                              void* d_out, int out_size, void* d_ws,
                              size_t ws_size, hipStream_t stream) {
  (void)in_sizes; (void)n_in; (void)out_size; (void)ws_size;
  const float* q = (const float*)d_in[0];
  const float* k = (const float*)d_in[1];
  const float* v = (const float*)d_in[2];
  const float* Wq = (const float*)d_in[3];
  const float* bq = (const float*)d_in[4];
  const float* Wk = (const float*)d_in[5];
  const float* bk = (const float*)d_in[6];
  const float* Wv = (const float*)d_in[7];
  const float* bv = (const float*)d_in[8];
  const float* Wo = (const float*)d_in[9];
  const float* bo = (const float*)d_in[10];
  const float* gamma = (const float*)d_in[11];
  const float* beta = (const float*)d_in[12];

  char* ws = (char*)d_ws;
  const size_t MiB = 1 << 20;
  u16* Wq_b = (u16*)(ws + 0 * MiB);
  u16* Wk_b = (u16*)(ws + 2 * MiB);
  u16* Wv_b = (u16*)(ws + 4 * MiB);
  u16* Wo_b = (u16*)(ws + 6 * MiB);
  u16* qb = (u16*)(ws + 8 * MiB);   // 16 MiB
  u16* kb = (u16*)(ws + 24 * MiB);  // 16 MiB
  u16* vb = (u16*)(ws + 40 * MiB);  // 16 MiB
  u16* Qh = (u16*)(ws + 56 * MiB);  // 16 MiB
  u16* Kh = (u16*)(ws + 8 * MiB);   // alias qb (dead after Q proj)
  u16* Vt = (u16*)(ws + 24 * MiB);  // alias kb (dead after K proj)
  u16* AO = (u16*)(ws + 40 * MiB);  // alias vb (dead after V proj)
  // total ws usage: 72 MiB

  const float scale = 0.125f;  // HD^-0.5, folded into Wq/bq

  cvt_kernel<<<512, 256, 0, stream>>>(Wq, Wq_b, DIM * DIM / 4, scale);
  cvt_kernel<<<512, 256, 0, stream>>>(Wk, Wk_b, DIM * DIM / 4, 1.f);
  cvt_kernel<<<512, 256, 0, stream>>>(Wv, Wv_b, DIM * DIM / 4, 1.f);
  cvt_kernel<<<512, 256, 0, stream>>>(Wo, Wo_b, DIM * DIM / 4, 1.f);
  cvt_kernel<<<2048, 256, 0, stream>>>(q, qb, MROWS * DIM / 4, 1.f);
  cvt_kernel<<<2048, 256, 0, stream>>>(k, kb, MROWS * DIM / 4, 1.f);
  cvt_kernel<<<2048, 256, 0, stream>>>(v, vb, MROWS * DIM / 4, 1.f);

  dim3 blk(256);
  // Q/K projections: M=8192 rows (tokens), N=1024 (channels)
  gemm_nt<EPI_QK><<<dim3(DIM / BN, MROWS / BM), blk, 0, stream>>>(
      qb, Wq_b, Qh, bq, scale, DIM);
  gemm_nt<EPI_QK><<<dim3(DIM / BN, MROWS / BM), blk, 0, stream>>>(
      kb, Wk_b, Kh, bk, 1.f, DIM);
  // V projection swapped: C'[i][j] = sum_k Wv[i][k] x[j][k] -> Vt [B,H,HD,S]
  gemm_nt<EPI_VT><<<dim3(MROWS / BN, DIM / BM), blk, 0, stream>>>(
      Wv_b, vb, Vt, bv, 1.f, DIM);

  attn_kernel<<<dim3(SEQ / 64, BATCH * NH), blk, 0, stream>>>(Qh, Kh, Vt, AO);

  // output projection -> fp32 directly into d_out
  gemm_nt<EPI_F32><<<dim3(DIM / BN, MROWS / BM), blk, 0, stream>>>(
      AO, Wo_b, (float*)d_out, bo, 1.f, DIM);

  // LayerNorm in place
  ln_kernel<<<MROWS, 256, 0, stream>>>((const float*)d_out, gamma, beta,
                                       (float*)d_out);
}

// Round 3
// 274.379 us; speedup vs baseline: 1.3453x; 1.3453x over previous
//
#include <hip/hip_runtime.h>

typedef unsigned short u16;
typedef __attribute__((ext_vector_type(8))) short bf16x8;
typedef __attribute__((ext_vector_type(4))) float f32x4;
typedef __attribute__((ext_vector_type(16))) float f32x16;
typedef __attribute__((ext_vector_type(4))) unsigned short u16x4;
typedef __attribute__((ext_vector_type(4))) unsigned int u32x4;
typedef __attribute__((ext_vector_type(2))) unsigned int u32x2;

#define DIM 1024
#define NH 16
#define HD 64
#define BATCH 4
#define SEQ 2048
#define MROWS (BATCH * SEQ)  // 8192

__device__ __forceinline__ u16 f2bf(float f) {
  unsigned u = __builtin_bit_cast(unsigned, f);
  return (u16)((u + 0x7fffu + ((u >> 16) & 1u)) >> 16);  // RNE
}

__device__ __forceinline__ void gload16(const u16* g, u16* l) {
  __builtin_amdgcn_global_load_lds(
      (const __attribute__((address_space(1))) void*)g,
      (__attribute__((address_space(3))) void*)l, 16, 0, 0);
}

__device__ __forceinline__ unsigned cvtpk(float lo, float hi) {
  unsigned r;
  asm("v_cvt_pk_bf16_f32 %0, %1, %2" : "=v"(r) : "v"(lo), "v"(hi));
  return r;
}

// v_permlane32_swap_b32 vdst, vsrc: vdst's high 32 lanes <-> vsrc's low 32 lanes.
// After: a = {lanes<32: old a; lanes>=32: partner-hi0's b}
//        b = {lanes<32: partner-hi1's a; lanes>=32: old b}
__device__ __forceinline__ void plswap(unsigned& a, unsigned& b) {
  asm("v_permlane32_swap_b32 %0, %1" : "+v"(a), "+v"(b));
}

// ---------------- fp32 -> bf16 conversion (optionally scaled) ----------------
__global__ __launch_bounds__(256) void cvt_kernel(const float* __restrict__ in,
                                                  u16* __restrict__ out,
                                                  int n4, float mul) {
  int i = blockIdx.x * blockDim.x + threadIdx.x;
  int stride = gridDim.x * blockDim.x;
  for (; i < n4; i += stride) {
    f32x4 v = ((const f32x4*)in)[i];
    u16x4 o;
    o[0] = f2bf(v[0] * mul);
    o[1] = f2bf(v[1] * mul);
    o[2] = f2bf(v[2] * mul);
    o[3] = f2bf(v[3] * mul);
    ((u16x4*)out)[i] = o;
  }
}

// ---------------- GEMM: C = A * B^T + bias, A[M][K], B[N][K] bf16 ----------------
enum { EPI_QK = 0, EPI_VT = 1, EPI_F32 = 2 };

#define BM 128
#define BN 128
#define BK 64

template <int EPI>
__global__ __launch_bounds__(256) void gemm_nt(const u16* __restrict__ A,
                                               const u16* __restrict__ Bm,
                                               void* __restrict__ C,
                                               const float* __restrict__ bias,
                                               float bscale, int Kdim) {
  __shared__ __attribute__((aligned(16))) u16 Alds[BM * BK];
  __shared__ __attribute__((aligned(16))) u16 Blds[BN * BK];

  const int tid = threadIdx.x;
  const int w = tid >> 6, l = tid & 63;
  const int wr = w >> 1, wc = w & 1;
  const int row0 = blockIdx.y * BM;
  const int col0 = blockIdx.x * BN;
  const int lr = l >> 3;  // row within 8-row chunk
  const int sp = l & 7;   // physical 16B slot

  f32x4 acc[4][4];
#pragma unroll
  for (int i = 0; i < 4; i++)
#pragma unroll
    for (int j = 0; j < 4; j++) {
      f32x4 z = {0.f, 0.f, 0.f, 0.f};
      acc[i][j] = z;
    }

  for (int k0 = 0; k0 < Kdim; k0 += BK) {
    __syncthreads();
#pragma unroll
    for (int q = 0; q < 4; q++) {
      int chunk = w * 4 + q;       // 0..15
      int r = chunk * 8 + lr;      // 0..127
      int sl = sp ^ (r & 7);       // logical slot this lane fetches
      gload16(A + (size_t)(row0 + r) * Kdim + k0 + sl * 8, &Alds[chunk * 512]);
      gload16(Bm + (size_t)(col0 + r) * Kdim + k0 + sl * 8, &Blds[chunk * 512]);
    }
    __syncthreads();

#pragma unroll
    for (int t = 0; t < 2; t++) {
      int slot = (t * 4 + (l >> 4)) ^ (l & 7);
      bf16x8 af[4], bf[4];
#pragma unroll
      for (int i = 0; i < 4; i++) {
        int arow = wr * 64 + i * 16 + (l & 15);
        af[i] = *(const bf16x8*)&Alds[arow * 64 + slot * 8];
        int brow = wc * 64 + i * 16 + (l & 15);
        bf[i] = *(const bf16x8*)&Blds[brow * 64 + slot * 8];
      }
#pragma unroll
      for (int i = 0; i < 4; i++)
#pragma unroll
        for (int j = 0; j < 4; j++)
          acc[i][j] = __builtin_amdgcn_mfma_f32_16x16x32_bf16(af[i], bf[j],
                                                              acc[i][j], 0, 0, 0);
    }
  }

#pragma unroll
  for (int i = 0; i < 4; i++) {
#pragma unroll
    for (int j = 0; j < 4; j++) {
#pragma unroll
      for (int q = 0; q < 4; q++) {
        int m = row0 + wr * 64 + i * 16 + (l >> 4) * 4 + q;
        int n = col0 + wc * 64 + j * 16 + (l & 15);
        float v = acc[i][j][q];
        if (EPI == EPI_QK) {
          v += bias[n] * bscale;
          int b_ = m >> 11, s_ = m & (SEQ - 1), h_ = n >> 6, hd_ = n & 63;
          ((u16*)C)[(((size_t)(b_ * NH + h_) * SEQ + s_) << 6) + hd_] = f2bf(v);
        } else if (EPI == EPI_VT) {
          v += bias[m];
          int b_ = n >> 11, s_ = n & (SEQ - 1);
          ((u16*)C)[((size_t)(b_ * NH + (m >> 6)) * HD + (m & 63)) * SEQ + s_] =
              f2bf(v);
        } else {
          v += bias[n];
          ((float*)C)[(size_t)m * DIM + n] = v;
        }
      }
    }
  }
}

// ---------------- flash attention, swapped-QK^T 32x32 ----------------
// grid (SEQ/128, BATCH*NH), 256 threads = 4 warps x 32 Q rows.
// Per warp: S^T = mfma32(K, Q): lane pair (l31, l31+32) both own q=l31;
// st{t}[r] = S[q][kv = t*32 + (r&3)+8*(r>>2)+4*hi]. In-register softmax
// (exp2 domain; HD^-0.5*log2e folded into Wq). P fragments via cvt_pk +
// permlane32_swap: pa[ks][j] = P[q][ks*16 + hi*8 + j] comes from owner_hi=j>>2,
// group g = 2*(ks&1)+hi -> swap(cw[t][2c], cw[t][2c+1]) gives (j0..3),(j4..7).
// O^T = mfma32(Vt, P^T): oacc{t'}[r] = O[q][d = t'*32 + (r&3)+8*(r>>2)+4*hi].
__global__ __launch_bounds__(256) void attn_kernel(const u16* __restrict__ Qh,
                                                   const u16* __restrict__ Kh,
                                                   const u16* __restrict__ Vt,
                                                   u16* __restrict__ AO) {
  __shared__ __attribute__((aligned(16))) u16 Klds[64 * 64];
  __shared__ __attribute__((aligned(16))) u16 Vlds[64 * 64];

  const int tid = threadIdx.x;
  const int w = tid >> 6, l = tid & 63;
  const int l31 = l & 31, hi = l >> 5;
  const int bh = blockIdx.y;
  const int qt = blockIdx.x;
  const int b_ = bh >> 4, h_ = bh & 15;
  const int lr = l >> 3, sp = l & 7;

  // Q fragments: qf[ks] = Q[q=l31][ks*16 + hi*8 + 0..7]
  const int qrow = qt * 128 + w * 32 + l31;
  const u16* qp = Qh + ((size_t)bh * SEQ + qrow) * HD + hi * 8;
  bf16x8 qf[4];
#pragma unroll
  for (int ks = 0; ks < 4; ks++) qf[ks] = *(const bf16x8*)(qp + ks * 16);

  f32x16 oacc0, oacc1;
#pragma unroll
  for (int r = 0; r < 16; r++) {
    oacc0[r] = 0.f;
    oacc1[r] = 0.f;
  }
  float mrun = -3.0e38f, lrun = 0.f;

  for (int kt = 0; kt < SEQ / 64; kt++) {
    __syncthreads();
#pragma unroll
    for (int q2 = 0; q2 < 2; q2++) {
      int chunk = w * 2 + q2;  // 0..7, 8 rows each
      int r = chunk * 8 + lr;
      int sl = sp ^ (r & 7);
      gload16(Kh + ((size_t)bh * SEQ + kt * 64 + r) * HD + sl * 8,
              &Klds[chunk * 512]);
      gload16(Vt + ((size_t)bh * HD + r) * SEQ + kt * 64 + sl * 8,
              &Vlds[chunk * 512]);
    }
    __syncthreads();

    // S^T = K Q^T
    f32x16 st0, st1;
#pragma unroll
    for (int r = 0; r < 16; r++) {
      st0[r] = 0.f;
      st1[r] = 0.f;
    }
#pragma unroll
    for (int ks = 0; ks < 4; ks++) {
      int slot = ((ks * 2 + hi) ^ (l & 7)) * 8;
      bf16x8 kf0 = *(const bf16x8*)&Klds[l31 * 64 + slot];
      bf16x8 kf1 = *(const bf16x8*)&Klds[(32 + l31) * 64 + slot];
      st0 = __builtin_amdgcn_mfma_f32_32x32x16_bf16(kf0, qf[ks], st0, 0, 0, 0);
      st1 = __builtin_amdgcn_mfma_f32_32x32x16_bf16(kf1, qf[ks], st1, 0, 0, 0);
    }

    // in-register online softmax (exp2 domain)
    float pm = st0[0];
#pragma unroll
    for (int r = 1; r < 16; r++) pm = fmaxf(pm, st0[r]);
#pragma unroll
    for (int r = 0; r < 16; r++) pm = fmaxf(pm, st1[r]);
    pm = fmaxf(pm, __shfl_xor(pm, 32));
    float mnew = fmaxf(mrun, pm);
    float fac = __builtin_amdgcn_exp2f(mrun - mnew);
    float ps = 0.f;
#pragma unroll
    for (int r = 0; r < 16; r++) {
      st0[r] = __builtin_amdgcn_exp2f(st0[r] - mnew);
      ps += st0[r];
    }
#pragma unroll
    for (int r = 0; r < 16; r++) {
      st1[r] = __builtin_amdgcn_exp2f(st1[r] - mnew);
      ps += st1[r];
    }
    ps += __shfl_xor(ps, 32);
    lrun = lrun * fac + ps;
    mrun = mnew;
#pragma unroll
    for (int r = 0; r < 16; r++) {
      oacc0[r] *= fac;
      oacc1[r] *= fac;
    }

    // P -> bf16 fragments. cw[t][g] packs st_t[4g..4g+3] as 2 words.
    unsigned cw[2][4][2];
#pragma unroll
    for (int g = 0; g < 4; g++) {
      cw[0][g][0] = cvtpk(st0[4 * g], st0[4 * g + 1]);
      cw[0][g][1] = cvtpk(st0[4 * g + 2], st0[4 * g + 3]);
      cw[1][g][0] = cvtpk(st1[4 * g], st1[4 * g + 1]);
      cw[1][g][1] = cvtpk(st1[4 * g + 2], st1[4 * g + 3]);
    }
    bf16x8 pa[4];
#pragma unroll
    for (int ks = 0; ks < 4; ks++) {
      int t = ks >> 1, c = ks & 1;
      unsigned a0 = cw[t][2 * c][0], b0 = cw[t][2 * c + 1][0];
      unsigned a1 = cw[t][2 * c][1], b1 = cw[t][2 * c + 1][1];
      plswap(a0, b0);  // a0 -> (j0,j1), b0 -> (j4,j5)
      plswap(a1, b1);  // a1 -> (j2,j3), b1 -> (j6,j7)
      u32x4 pw;
      pw[0] = a0;
      pw[1] = a1;
      pw[2] = b0;
      pw[3] = b1;
      pa[ks] = __builtin_bit_cast(bf16x8, pw);
    }

    // O^T += Vt P^T
#pragma unroll
    for (int ks = 0; ks < 4; ks++) {
      int slot = ((ks * 2 + hi) ^ (l & 7)) * 8;
      bf16x8 vf0 = *(const bf16x8*)&Vlds[l31 * 64 + slot];
      bf16x8 vf1 = *(const bf16x8*)&Vlds[(32 + l31) * 64 + slot];
      oacc0 = __builtin_amdgcn_mfma_f32_32x32x16_bf16(vf0, pa[ks], oacc0, 0, 0, 0);
      oacc1 = __builtin_amdgcn_mfma_f32_32x32x16_bf16(vf1, pa[ks], oacc1, 0, 0, 0);
    }
  }

  // epilogue: group g covers d = 8g + 4*hi + 0..3 (and +32 for oacc1)
  float rinv = 1.f / lrun;
  u16* orow = AO + ((size_t)b_ * SEQ + qrow) * DIM + h_ * HD;
#pragma unroll
  for (int g = 0; g < 4; g++) {
    u32x2 s0, s1;
    s0[0] = cvtpk(oacc0[4 * g] * rinv, oacc0[4 * g + 1] * rinv);
    s0[1] = cvtpk(oacc0[4 * g + 2] * rinv, oacc0[4 * g + 3] * rinv);
    s1[0] = cvtpk(oacc1[4 * g] * rinv, oacc1[4 * g + 1] * rinv);
    s1[1] = cvtpk(oacc1[4 * g + 2] * rinv, oacc1[4 * g + 3] * rinv);
    *(u32x2*)(orow + 8 * g + 4 * hi) = s0;
    *(u32x2*)(orow + 32 + 8 * g + 4 * hi) = s1;
  }
}

// ---------------- LayerNorm ----------------
__global__ __launch_bounds__(256) void ln_kernel(const float* __restrict__ X,
                                                 const float* __restrict__ gamma,
                                                 const float* __restrict__ beta,
                                                 float* __restrict__ out) {
  __shared__ float red[8];
  const int row = blockIdx.x;
  const int tid = threadIdx.x;
  const float* xr = X + (size_t)row * DIM;
  f32x4 v = ((const f32x4*)xr)[tid];
  float s = v[0] + v[1] + v[2] + v[3];
  float ss = v[0] * v[0] + v[1] * v[1] + v[2] * v[2] + v[3] * v[3];
#pragma unroll
  for (int mm = 1; mm <= 32; mm <<= 1) {
    s += __shfl_xor(s, mm);
    ss += __shfl_xor(ss, mm);
  }
  const int w = tid >> 6, l = tid & 63;
  if (l == 0) {
    red[w * 2] = s;
    red[w * 2 + 1] = ss;
  }
  __syncthreads();
  s = red[0] + red[2] + red[4] + red[6];
  ss = red[1] + red[3] + red[5] + red[7];
  float mu = s * (1.f / DIM);
  float var = ss * (1.f / DIM) - mu * mu;
  float rstd = rsqrtf(var + 1e-5f);
  f32x4 g = ((const f32x4*)gamma)[tid];
  f32x4 bt = ((const f32x4*)beta)[tid];
  f32x4 o;
#pragma unroll
  for (int j = 0; j < 4; j++) o[j] = (v[j] - mu) * rstd * g[j] + bt[j];
  ((f32x4*)(out + (size_t)row * DIM))[tid] = o;
}

// ---------------- launch ----------------
extern "C" void kernel_launch(void* const* d_in, const int* in_sizes, int n_in,
                              void* d_out, int out_size, void* d_ws,
                              size_t ws_size, hipStream_t stream) {
  (void)in_sizes; (void)n_in; (void)out_size; (void)ws_size;
  const float* q = (const float*)d_in[0];
  const float* k = (const float*)d_in[1];
  const float* v = (const float*)d_in[2];
  const float* Wq = (const float*)d_in[3];
  const float* bq = (const float*)d_in[4];
  const float* Wk = (const float*)d_in[5];
  const float* bk = (const float*)d_in[6];
  const float* Wv = (const float*)d_in[7];
  const float* bv = (const float*)d_in[8];
  const float* Wo = (const float*)d_in[9];
  const float* bo = (const float*)d_in[10];
  const float* gamma = (const float*)d_in[11];
  const float* beta = (const float*)d_in[12];

  char* ws = (char*)d_ws;
  const size_t MiB = 1 << 20;
  u16* Wq_b = (u16*)(ws + 0 * MiB);
  u16* Wk_b = (u16*)(ws + 2 * MiB);
  u16* Wv_b = (u16*)(ws + 4 * MiB);
  u16* Wo_b = (u16*)(ws + 6 * MiB);
  u16* qb = (u16*)(ws + 8 * MiB);
  u16* kb = (u16*)(ws + 24 * MiB);
  u16* vb = (u16*)(ws + 40 * MiB);
  u16* Qh = (u16*)(ws + 56 * MiB);
  u16* Kh = (u16*)(ws + 8 * MiB);   // alias qb
  u16* Vt = (u16*)(ws + 24 * MiB);  // alias kb
  u16* AO = (u16*)(ws + 40 * MiB);  // alias vb

  // HD^-0.5 * log2(e): scores land in exp2 domain
  const float scale = 0.125f * 1.44269504088896f;

  cvt_kernel<<<512, 256, 0, stream>>>(Wq, Wq_b, DIM * DIM / 4, scale);
  cvt_kernel<<<512, 256, 0, stream>>>(Wk, Wk_b, DIM * DIM / 4, 1.f);
  cvt_kernel<<<512, 256, 0, stream>>>(Wv, Wv_b, DIM * DIM / 4, 1.f);
  cvt_kernel<<<512, 256, 0, stream>>>(Wo, Wo_b, DIM * DIM / 4, 1.f);
  cvt_kernel<<<2048, 256, 0, stream>>>(q, qb, MROWS * DIM / 4, 1.f);
  cvt_kernel<<<2048, 256, 0, stream>>>(k, kb, MROWS * DIM / 4, 1.f);
  cvt_kernel<<<2048, 256, 0, stream>>>(v, vb, MROWS * DIM / 4, 1.f);

  dim3 blk(256);
  gemm_nt<EPI_QK><<<dim3(DIM / BN, MROWS / BM), blk, 0, stream>>>(
      qb, Wq_b, Qh, bq, scale, DIM);
  gemm_nt<EPI_QK><<<dim3(DIM / BN, MROWS / BM), blk, 0, stream>>>(
      kb, Wk_b, Kh, bk, 1.f, DIM);
  gemm_nt<EPI_VT><<<dim3(MROWS / BN, DIM / BM), blk, 0, stream>>>(
      Wv_b, vb, Vt, bv, 1.f, DIM);

  attn_kernel<<<dim3(SEQ / 128, BATCH * NH), blk, 0, stream>>>(Qh, Kh, Vt, AO);

  gemm_nt<EPI_F32><<<dim3(DIM / BN, MROWS / BM), blk, 0, stream>>>(
      AO, Wo_b, (float*)d_out, bo, 1.f, DIM);

  ln_kernel<<<MROWS, 256, 0, stream>>>((const float*)d_out, gamma, beta,
                                       (float*)d_out);
}

// Round 4
// 269.883 us; speedup vs baseline: 1.3677x; 1.0167x over previous
//
#include <hip/hip_runtime.h>

typedef unsigned short u16;
typedef __attribute__((ext_vector_type(8))) short bf16x8;
typedef __attribute__((ext_vector_type(4))) float f32x4;
typedef __attribute__((ext_vector_type(16))) float f32x16;
typedef __attribute__((ext_vector_type(4))) unsigned short u16x4;
typedef __attribute__((ext_vector_type(4))) unsigned int u32x4;
typedef __attribute__((ext_vector_type(2))) unsigned int u32x2;

#define DIM 1024
#define NH 16
#define HD 64
#define BATCH 4
#define SEQ 2048
#define MROWS (BATCH * SEQ)  // 8192

__device__ __forceinline__ u16 f2bf(float f) {
  unsigned u = __builtin_bit_cast(unsigned, f);
  return (u16)((u + 0x7fffu + ((u >> 16) & 1u)) >> 16);  // RNE
}

__device__ __forceinline__ void gload16(const u16* g, u16* l) {
  __builtin_amdgcn_global_load_lds(
      (const __attribute__((address_space(1))) void*)g,
      (__attribute__((address_space(3))) void*)l, 16, 0, 0);
}

__device__ __forceinline__ unsigned cvtpk(float lo, float hi) {
  unsigned r;
  asm("v_cvt_pk_bf16_f32 %0, %1, %2" : "=v"(r) : "v"(lo), "v"(hi));
  return r;
}

// v_permlane32_swap_b32 vdst, vsrc: vdst's high 32 lanes <-> vsrc's low 32 lanes.
__device__ __forceinline__ void plswap(unsigned& a, unsigned& b) {
  asm("v_permlane32_swap_b32 %0, %1" : "+v"(a), "+v"(b));
}

// ---------------- weights fp32 -> bf16 (Wq scaled), 4 segments ----------------
__global__ __launch_bounds__(256) void cvtw_kernel(const float* __restrict__ Wq,
                                                   const float* __restrict__ Wk,
                                                   const float* __restrict__ Wv,
                                                   const float* __restrict__ Wo,
                                                   u16* __restrict__ dst,
                                                   float scale) {
  int i = blockIdx.x * blockDim.x + threadIdx.x;  // 0 .. 4*2^18
  int seg = i >> 18;
  int off = i & ((1 << 18) - 1);
  const float* src = (seg == 0) ? Wq : (seg == 1) ? Wk : (seg == 2) ? Wv : Wo;
  float mul = (seg == 0) ? scale : 1.f;
  f32x4 v = ((const f32x4*)src)[off];
  u16x4 o;
  o[0] = f2bf(v[0] * mul);
  o[1] = f2bf(v[1] * mul);
  o[2] = f2bf(v[2] * mul);
  o[3] = f2bf(v[3] * mul);
  ((u16x4*)dst)[i] = o;
}

// ---------------- GEMM: C = A * B^T + bias; A[M][K], B[N][K] ----------------
// AF32/BF32: that operand is fp32 in global, converted to bf16 during staging.
enum { EPI_QK = 0, EPI_VT = 1, EPI_F32 = 2 };

#define BM 128
#define BN 128
#define BK 64

template <int EPI, bool AF32, bool BF32>
__global__ __launch_bounds__(256) void gemm_nt(const void* __restrict__ Ap,
                                               const void* __restrict__ Bp,
                                               void* __restrict__ C,
                                               const float* __restrict__ bias,
                                               float bscale, int Kdim) {
  __shared__ __attribute__((aligned(16))) u16 Alds[BM * BK];
  __shared__ __attribute__((aligned(16))) u16 Blds[BN * BK];

  const int tid = threadIdx.x;
  const int w = tid >> 6, l = tid & 63;
  const int wr = w >> 1, wc = w & 1;
  const int row0 = blockIdx.y * BM;
  const int col0 = blockIdx.x * BN;
  const int lr = l >> 3;  // row within 8-row chunk
  const int sp = l & 7;   // 16B slot

  f32x4 acc[4][4];
#pragma unroll
  for (int i = 0; i < 4; i++)
#pragma unroll
    for (int j = 0; j < 4; j++) {
      f32x4 z = {0.f, 0.f, 0.f, 0.f};
      acc[i][j] = z;
    }

  for (int k0 = 0; k0 < Kdim; k0 += BK) {
    __syncthreads();
#pragma unroll
    for (int q = 0; q < 4; q++) {
      int chunk = w * 4 + q;       // 0..15
      int r = chunk * 8 + lr;      // 0..127
      int sl = sp ^ (r & 7);       // physical slot for logical slot sp
      if constexpr (AF32) {
        const float* s = (const float*)Ap + (size_t)(row0 + r) * Kdim + k0 + sp * 8;
        f32x4 v0 = *(const f32x4*)s;
        f32x4 v1 = *(const f32x4*)(s + 4);
        u32x4 pk;
        pk[0] = cvtpk(v0[0], v0[1]);
        pk[1] = cvtpk(v0[2], v0[3]);
        pk[2] = cvtpk(v1[0], v1[1]);
        pk[3] = cvtpk(v1[2], v1[3]);
        *(u32x4*)&Alds[r * 64 + sl * 8] = pk;
      } else {
        gload16((const u16*)Ap + (size_t)(row0 + r) * Kdim + k0 + sl * 8,
                &Alds[chunk * 512]);
      }
      if constexpr (BF32) {
        const float* s = (const float*)Bp + (size_t)(col0 + r) * Kdim + k0 + sp * 8;
        f32x4 v0 = *(const f32x4*)s;
        f32x4 v1 = *(const f32x4*)(s + 4);
        u32x4 pk;
        pk[0] = cvtpk(v0[0], v0[1]);
        pk[1] = cvtpk(v0[2], v0[3]);
        pk[2] = cvtpk(v1[0], v1[1]);
        pk[3] = cvtpk(v1[2], v1[3]);
        *(u32x4*)&Blds[r * 64 + sl * 8] = pk;
      } else {
        gload16((const u16*)Bp + (size_t)(col0 + r) * Kdim + k0 + sl * 8,
                &Blds[chunk * 512]);
      }
    }
    __syncthreads();

#pragma unroll
    for (int t = 0; t < 2; t++) {
      int slot = (t * 4 + (l >> 4)) ^ (l & 7);
      bf16x8 af[4], bf[4];
#pragma unroll
      for (int i = 0; i < 4; i++) {
        int arow = wr * 64 + i * 16 + (l & 15);
        af[i] = *(const bf16x8*)&Alds[arow * 64 + slot * 8];
        int brow = wc * 64 + i * 16 + (l & 15);
        bf[i] = *(const bf16x8*)&Blds[brow * 64 + slot * 8];
      }
      __builtin_amdgcn_s_setprio(1);
#pragma unroll
      for (int i = 0; i < 4; i++)
#pragma unroll
        for (int j = 0; j < 4; j++)
          acc[i][j] = __builtin_amdgcn_mfma_f32_16x16x32_bf16(af[i], bf[j],
                                                              acc[i][j], 0, 0, 0);
      __builtin_amdgcn_s_setprio(0);
    }
  }

#pragma unroll
  for (int i = 0; i < 4; i++) {
#pragma unroll
    for (int j = 0; j < 4; j++) {
#pragma unroll
      for (int q = 0; q < 4; q++) {
        int m = row0 + wr * 64 + i * 16 + (l >> 4) * 4 + q;
        int n = col0 + wc * 64 + j * 16 + (l & 15);
        float v = acc[i][j][q];
        if (EPI == EPI_QK) {
          v += bias[n] * bscale;
          int b_ = m >> 11, s_ = m & (SEQ - 1), h_ = n >> 6, hd_ = n & 63;
          ((u16*)C)[(((size_t)(b_ * NH + h_) * SEQ + s_) << 6) + hd_] = f2bf(v);
        } else if (EPI == EPI_VT) {
          v += bias[m];
          int b_ = n >> 11, s_ = n & (SEQ - 1);
          ((u16*)C)[((size_t)(b_ * NH + (m >> 6)) * HD + (m & 63)) * SEQ + s_] =
              f2bf(v);
        } else {
          v += bias[n];
          ((float*)C)[(size_t)m * DIM + n] = v;
        }
      }
    }
  }
}

// ---------------- flash attention, swapped-QK^T 32x32, double-buffered ----------------
__global__ __launch_bounds__(256) void attn_kernel(const u16* __restrict__ Qh,
                                                   const u16* __restrict__ Kh,
                                                   const u16* __restrict__ Vt,
                                                   u16* __restrict__ AO) {
  __shared__ __attribute__((aligned(16))) u16 Klds[2][64 * 64];
  __shared__ __attribute__((aligned(16))) u16 Vlds[2][64 * 64];

  const int tid = threadIdx.x;
  const int w = tid >> 6, l = tid & 63;
  const int l31 = l & 31, hi = l >> 5;
  const int bh = blockIdx.y;
  const int qt = blockIdx.x;
  const int b_ = bh >> 4, h_ = bh & 15;
  const int lr = l >> 3, sp = l & 7;

  // Q fragments: qf[ks] = Q[q=l31][ks*16 + hi*8 + 0..7]
  const int qrow = qt * 128 + w * 32 + l31;
  const u16* qp = Qh + ((size_t)bh * SEQ + qrow) * HD + hi * 8;
  bf16x8 qf[4];
#pragma unroll
  for (int ks = 0; ks < 4; ks++) qf[ks] = *(const bf16x8*)(qp + ks * 16);

  f32x16 oacc0, oacc1;
#pragma unroll
  for (int r = 0; r < 16; r++) {
    oacc0[r] = 0.f;
    oacc1[r] = 0.f;
  }
  float mrun = -3.0e38f, lrun = 0.f;

  const int chunk = w * 2;  // this wave stages chunks {chunk, chunk+1} of K and V
  const int r0 = chunk * 8 + lr, r1 = r0 + 8;
  const int sl0 = sp ^ (lr & 7);  // r0&7 == r1&7 == lr
  const size_t kbase = (size_t)bh * SEQ * HD;
  const size_t vbase = (size_t)bh * HD * SEQ;

#define ISSUE(kt, buf)                                                        \
  do {                                                                        \
    gload16(Kh + kbase + ((kt) * 64 + r0) * HD + sl0 * 8,                     \
            &Klds[buf][chunk * 512]);                                         \
    gload16(Vt + vbase + (size_t)r0 * SEQ + (kt) * 64 + sl0 * 8,              \
            &Vlds[buf][chunk * 512]);                                         \
    gload16(Kh + kbase + ((kt) * 64 + r1) * HD + sl0 * 8,                     \
            &Klds[buf][chunk * 512 + 512]);                                   \
    gload16(Vt + vbase + (size_t)r1 * SEQ + (kt) * 64 + sl0 * 8,              \
            &Vlds[buf][chunk * 512 + 512]);                                   \
  } while (0)

  ISSUE(0, 0);

  for (int kt = 0; kt < SEQ / 64; kt++) {
    const int cur = kt & 1;
    if (kt < SEQ / 64 - 1) {
      ISSUE(kt + 1, cur ^ 1);
      asm volatile("s_waitcnt vmcnt(4)" ::: "memory");
    } else {
      asm volatile("s_waitcnt vmcnt(0)" ::: "memory");
    }
    __builtin_amdgcn_s_barrier();
    __builtin_amdgcn_sched_barrier(0);

    const u16* Kc = Klds[cur];
    const u16* Vc = Vlds[cur];

    // S^T = K Q^T
    f32x16 st0, st1;
#pragma unroll
    for (int r = 0; r < 16; r++) {
      st0[r] = 0.f;
      st1[r] = 0.f;
    }
    __builtin_amdgcn_s_setprio(1);
#pragma unroll
    for (int ks = 0; ks < 4; ks++) {
      int slot = ((ks * 2 + hi) ^ (l & 7)) * 8;
      bf16x8 kf0 = *(const bf16x8*)&Kc[l31 * 64 + slot];
      bf16x8 kf1 = *(const bf16x8*)&Kc[(32 + l31) * 64 + slot];
      st0 = __builtin_amdgcn_mfma_f32_32x32x16_bf16(kf0, qf[ks], st0, 0, 0, 0);
      st1 = __builtin_amdgcn_mfma_f32_32x32x16_bf16(kf1, qf[ks], st1, 0, 0, 0);
    }
    __builtin_amdgcn_s_setprio(0);

    // max via v_max3 tree
    float pm = fmaxf(st0[0], st0[1]);
#pragma unroll
    for (int r = 2; r < 16; r += 2) pm = fmaxf(fmaxf(pm, st0[r]), st0[r + 1]);
#pragma unroll
    for (int r = 0; r < 16; r += 2) pm = fmaxf(fmaxf(pm, st1[r]), st1[r + 1]);
    pm = fmaxf(pm, __shfl_xor(pm, 32));

    // defer-max: rescale only when some row's max grew past THR=8 (exp2 units)
    if (!__all(pm <= mrun + 8.f)) {
      float mnew = fmaxf(mrun, pm);
      float fac = __builtin_amdgcn_exp2f(mrun - mnew);
      lrun *= fac;
#pragma unroll
      for (int r = 0; r < 16; r++) {
        oacc0[r] *= fac;
        oacc1[r] *= fac;
      }
      mrun = mnew;
    }

    float ps = 0.f;
#pragma unroll
    for (int r = 0; r < 16; r++) {
      st0[r] = __builtin_amdgcn_exp2f(st0[r] - mrun);
      ps += st0[r];
    }
#pragma unroll
    for (int r = 0; r < 16; r++) {
      st1[r] = __builtin_amdgcn_exp2f(st1[r] - mrun);
      ps += st1[r];
    }
    ps += __shfl_xor(ps, 32);
    lrun += ps;

    // P -> bf16 fragments
    unsigned cw[2][4][2];
#pragma unroll
    for (int g = 0; g < 4; g++) {
      cw[0][g][0] = cvtpk(st0[4 * g], st0[4 * g + 1]);
      cw[0][g][1] = cvtpk(st0[4 * g + 2], st0[4 * g + 3]);
      cw[1][g][0] = cvtpk(st1[4 * g], st1[4 * g + 1]);
      cw[1][g][1] = cvtpk(st1[4 * g + 2], st1[4 * g + 3]);
    }
    bf16x8 pa[4];
#pragma unroll
    for (int ks = 0; ks < 4; ks++) {
      int t = ks >> 1, c = ks & 1;
      unsigned a0 = cw[t][2 * c][0], b0 = cw[t][2 * c + 1][0];
      unsigned a1 = cw[t][2 * c][1], b1 = cw[t][2 * c + 1][1];
      plswap(a0, b0);  // a0 -> (j0,j1), b0 -> (j4,j5)
      plswap(a1, b1);  // a1 -> (j2,j3), b1 -> (j6,j7)
      u32x4 pw;
      pw[0] = a0;
      pw[1] = a1;
      pw[2] = b0;
      pw[3] = b1;
      pa[ks] = __builtin_bit_cast(bf16x8, pw);
    }

    // O^T += Vt P^T
    __builtin_amdgcn_s_setprio(1);
#pragma unroll
    for (int ks = 0; ks < 4; ks++) {
      int slot = ((ks * 2 + hi) ^ (l & 7)) * 8;
      bf16x8 vf0 = *(const bf16x8*)&Vc[l31 * 64 + slot];
      bf16x8 vf1 = *(const bf16x8*)&Vc[(32 + l31) * 64 + slot];
      oacc0 = __builtin_amdgcn_mfma_f32_32x32x16_bf16(vf0, pa[ks], oacc0, 0, 0, 0);
      oacc1 = __builtin_amdgcn_mfma_f32_32x32x16_bf16(vf1, pa[ks], oacc1, 0, 0, 0);
    }
    __builtin_amdgcn_s_setprio(0);

    asm volatile("" ::: "memory");
    __builtin_amdgcn_s_barrier();
    __builtin_amdgcn_sched_barrier(0);
  }

  // epilogue
  float rinv = 1.f / lrun;
  u16* orow = AO + ((size_t)b_ * SEQ + qrow) * DIM + h_ * HD;
#pragma unroll
  for (int g = 0; g < 4; g++) {
    u32x2 s0, s1;
    s0[0] = cvtpk(oacc0[4 * g] * rinv, oacc0[4 * g + 1] * rinv);
    s0[1] = cvtpk(oacc0[4 * g + 2] * rinv, oacc0[4 * g + 3] * rinv);
    s1[0] = cvtpk(oacc1[4 * g] * rinv, oacc1[4 * g + 1] * rinv);
    s1[1] = cvtpk(oacc1[4 * g + 2] * rinv, oacc1[4 * g + 3] * rinv);
    *(u32x2*)(orow + 8 * g + 4 * hi) = s0;
    *(u32x2*)(orow + 32 + 8 * g + 4 * hi) = s1;
  }
}

// ---------------- LayerNorm ----------------
__global__ __launch_bounds__(256) void ln_kernel(const float* __restrict__ X,
                                                 const float* __restrict__ gamma,
                                                 const float* __restrict__ beta,
                                                 float* __restrict__ out) {
  __shared__ float red[8];
  const int row = blockIdx.x;
  const int tid = threadIdx.x;
  const float* xr = X + (size_t)row * DIM;
  f32x4 v = ((const f32x4*)xr)[tid];
  float s = v[0] + v[1] + v[2] + v[3];
  float ss = v[0] * v[0] + v[1] * v[1] + v[2] * v[2] + v[3] * v[3];
#pragma unroll
  for (int mm = 1; mm <= 32; mm <<= 1) {
    s += __shfl_xor(s, mm);
    ss += __shfl_xor(ss, mm);
  }
  const int w = tid >> 6, l = tid & 63;
  if (l == 0) {
    red[w * 2] = s;
    red[w * 2 + 1] = ss;
  }
  __syncthreads();
  s = red[0] + red[2] + red[4] + red[6];
  ss = red[1] + red[3] + red[5] + red[7];
  float mu = s * (1.f / DIM);
  float var = ss * (1.f / DIM) - mu * mu;
  float rstd = rsqrtf(var + 1e-5f);
  f32x4 g = ((const f32x4*)gamma)[tid];
  f32x4 bt = ((const f32x4*)beta)[tid];
  f32x4 o;
#pragma unroll
  for (int j = 0; j < 4; j++) o[j] = (v[j] - mu) * rstd * g[j] + bt[j];
  ((f32x4*)(out + (size_t)row * DIM))[tid] = o;
}

// ---------------- launch ----------------
extern "C" void kernel_launch(void* const* d_in, const int* in_sizes, int n_in,
                              void* d_out, int out_size, void* d_ws,
                              size_t ws_size, hipStream_t stream) {
  (void)in_sizes; (void)n_in; (void)out_size; (void)ws_size;
  const float* q = (const float*)d_in[0];
  const float* k = (const float*)d_in[1];
  const float* v = (const float*)d_in[2];
  const float* Wq = (const float*)d_in[3];
  const float* bq = (const float*)d_in[4];
  const float* Wk = (const float*)d_in[5];
  const float* bk = (const float*)d_in[6];
  const float* Wv = (const float*)d_in[7];
  const float* bv = (const float*)d_in[8];
  const float* Wo = (const float*)d_in[9];
  const float* bo = (const float*)d_in[10];
  const float* gamma = (const float*)d_in[11];
  const float* beta = (const float*)d_in[12];

  char* ws = (char*)d_ws;
  const size_t MiB = 1 << 20;
  u16* Wb = (u16*)(ws + 0 * MiB);  // 8 MiB: Wq,Wk,Wv,Wo bf16 contiguous
  u16* Wq_b = Wb;
  u16* Wk_b = (u16*)(ws + 2 * MiB);
  u16* Wv_b = (u16*)(ws + 4 * MiB);
  u16* Wo_b = (u16*)(ws + 6 * MiB);
  u16* Qh = (u16*)(ws + 8 * MiB);   // 16 MiB [B,H,S,HD]
  u16* Kh = (u16*)(ws + 24 * MiB);  // 16 MiB [B,H,S,HD]
  u16* Vt = (u16*)(ws + 40 * MiB);  // 16 MiB [B,H,HD,S]
  u16* AO = (u16*)(ws + 56 * MiB);  // 16 MiB [B,S,DIM]

  // HD^-0.5 * log2(e): scores land in exp2 domain
  const float scale = 0.125f * 1.44269504088896f;

  cvtw_kernel<<<4096, 256, 0, stream>>>(Wq, Wk, Wv, Wo, Wb, scale);

  dim3 blk(256);
  gemm_nt<EPI_QK, true, false><<<dim3(DIM / BN, MROWS / BM), blk, 0, stream>>>(
      q, Wq_b, Qh, bq, scale, DIM);
  gemm_nt<EPI_QK, true, false><<<dim3(DIM / BN, MROWS / BM), blk, 0, stream>>>(
      k, Wk_b, Kh, bk, 1.f, DIM);
  gemm_nt<EPI_VT, false, true><<<dim3(MROWS / BN, DIM / BM), blk, 0, stream>>>(
      Wv_b, v, Vt, bv, 1.f, DIM);

  attn_kernel<<<dim3(SEQ / 128, BATCH * NH), blk, 0, stream>>>(Qh, Kh, Vt, AO);

  gemm_nt<EPI_F32, false, false><<<dim3(DIM / BN, MROWS / BM), blk, 0, stream>>>(
      AO, Wo_b, (float*)d_out, bo, 1.f, DIM);

  ln_kernel<<<MROWS, 256, 0, stream>>>((const float*)d_out, gamma, beta,
                                       (float*)d_out);
}